// Round 19
// baseline (75.510 us; speedup 1.0000x reference)
//
#include <hip/hip_runtime.h>
#include <math.h>

#define N 80
#define D 512
#define NV (N*N)        // 6400
#define CQ 6241.000001  // (n1-1)*(n2-1) + ridge
#define NEU_K 2         // truncation ~ ||r||/CQ^3 ~ 1.6e-10

// ---- static device scratch (f32 front-end) ----
__device__ float g_Mp0[N*N];
__device__ float g_WT[D*D];         // W transposed
__device__ float g_e[2][N*D];       // normalized embeddings
__device__ float g_P[NV];           // p[v], v = i2*80 + i1

// k_pre: blocks 0..255 transpose W into WT (32x32 LDS tiles);
//        blocks 256..455 compute Mp0 = d1 @ d2^T (8 threads/output, f32).
__global__ void k_pre(const float* __restrict__ W,
                      const float* __restrict__ d1, const float* __restrict__ d2) {
    int bid = blockIdx.x;
    int tid = threadIdx.x;
    if (bid < 256) {
        __shared__ float t[32][33];
        int c0 = (bid & 15)*32, k0 = (bid >> 4)*32;
        int tx = tid & 31, ty = tid >> 5;       // 32 x 8
        #pragma unroll
        for (int j = 0; j < 4; ++j) t[ty+8*j][tx] = W[(size_t)(k0+ty+8*j)*D + c0+tx];
        __syncthreads();
        #pragma unroll
        for (int j = 0; j < 4; ++j) g_WT[(size_t)(c0+ty+8*j)*D + k0+tx] = t[tx][ty+8*j];
    } else {
        int gidx = (bid-256)*256 + tid;         // 51200 threads
        int v = gidx >> 3, ch = gidx & 7;
        int i = v / N, j = v % N;
        const float4* A = reinterpret_cast<const float4*>(d1 + (size_t)i*D);
        const float4* B = reinterpret_cast<const float4*>(d2 + (size_t)j*D);
        float a0=0,a1=0,a2=0,a3=0;
        #pragma unroll
        for (int t = 0; t < 16; ++t) {
            float4 x = A[ch + 8*t], y = B[ch + 8*t];
            a0 += x.x*y.x; a1 += x.y*y.y;
            a2 += x.z*y.z; a3 += x.w*y.w;
        }
        float s = (a0+a1)+(a2+a3);
        #pragma unroll
        for (int o = 1; o < 8; o <<= 1) s += __shfl_xor(s, o, 64);
        if (ch == 0) g_Mp0[i*N+j] = s;
    }
}

// block-wide (512 thr) f32 sum via wave shuffle + 8-slot LDS
__device__ __forceinline__ float bsum512f(float v, float* w8, int tid) {
    #pragma unroll
    for (int o = 1; o < 64; o <<= 1) v += __shfl_xor(v, o, 64);
    if ((tid & 63) == 0) w8[tid >> 6] = v;
    __syncthreads();
    return ((w8[0]+w8[1])+(w8[2]+w8[3])) + ((w8[4]+w8[5])+(w8[6]+w8[7]));
}

// k_mue: fused m -> lam -> u -> e -> normalize for TWO rows per block.
// 80 blocks x 512 threads; thread k owns output column k for both rows.
// WT element loaded once feeds both rows (halves W traffic to 80 MB).
__global__ void __launch_bounds__(512,1) k_mue(const float* __restrict__ d1,
                                               const float* __restrict__ d2,
                                               const float* __restrict__ b) {
    __shared__ float mp0[N], mp1[N];
    __shared__ float su0[D], su1[D];
    __shared__ float w8a[8], w8b[8];
    int bid = blockIdx.x;          // 0..79
    int g = bid / 40;
    int r0 = (bid % 40) * 2;       // rows r0, r0+1 of graph g
    int tid = threadIdx.x;         // = column k
    const float* dsrc = g ? d1 : d2;    // rows summed into m
    const float* dme  = g ? d2 : d1;    // own data rows

    if (tid < N) {
        mp0[tid] = g ? g_Mp0[tid*N + r0] : g_Mp0[r0*N + tid];
    } else if (tid < 2*N) {
        int j = tid - N;
        mp1[j] = g ? g_Mp0[j*N + (r0+1)] : g_Mp0[(r0+1)*N + j];
    }
    __syncthreads();

    // m_k for both rows; dsrc load shared (4 chains x 2 rows)
    float ma0=0,ma1=0,ma2=0,ma3=0, mb0=0,mb1=0,mb2=0,mb3=0;
    #pragma unroll 4
    for (int j = 0; j < N; j += 4) {
        float w0 = dsrc[(size_t)j*D     + tid];
        float w1 = dsrc[(size_t)(j+1)*D + tid];
        float w2 = dsrc[(size_t)(j+2)*D + tid];
        float w3 = dsrc[(size_t)(j+3)*D + tid];
        ma0 += mp0[j]*w0; ma1 += mp0[j+1]*w1; ma2 += mp0[j+2]*w2; ma3 += mp0[j+3]*w3;
        mb0 += mp1[j]*w0; mb1 += mp1[j+1]*w1; mb2 += mp1[j+2]*w2; mb3 += mp1[j+3]*w3;
    }
    float mk0 = (ma0+ma1)+(ma2+ma3);
    float mk1 = (mb0+mb1)+(mb2+mb3);
    float ak0 = dme[(size_t)r0*D + tid];
    float ak1 = dme[(size_t)(r0+1)*D + tid];

    float sa0 = bsum512f(ak0*ak0, w8a, tid);
    float sm0 = bsum512f(mk0*mk0, w8b, tid);
    __syncthreads();
    float sa1 = bsum512f(ak1*ak1, w8a, tid);
    float sm1 = bsum512f(mk1*mk1, w8b, tid);
    float lam0 = sqrtf(sa0) / sqrtf(sm0);
    float lam1 = sqrtf(sa1) / sqrtf(sm1);
    __syncthreads();
    su0[tid] = ak0 + lam0*mk0;
    su1[tid] = ak1 + lam1*mk1;
    __syncthreads();

    // e_k for both rows: one WT load feeds 2 FMAs; 16 loads in flight
    const float* wt = g_WT + tid;
    float A[16], B[16];
    #pragma unroll
    for (int q = 0; q < 16; ++q) { A[q] = 0.0f; B[q] = 0.0f; }
    for (int t = 0; t < 32; ++t) {
        int c = t*16;
        #pragma unroll
        for (int q = 0; q < 16; ++q) {
            float w = wt[(size_t)(c+q)*D];
            A[q] += su0[c+q]*w;
            B[q] += su1[c+q]*w;
        }
    }
    float accA = 0.0f, accB = 0.0f;
    #pragma unroll
    for (int q = 0; q < 16; ++q) { accA += A[q]; accB += B[q]; }
    float bk = b[tid];
    float ek0 = accA + bk; ek0 = ek0 > 0.0f ? ek0 : 0.0f;
    float ek1 = accB + bk; ek1 = ek1 > 0.0f ? ek1 : 0.0f;

    float sn0 = bsum512f(ek0*ek0, w8a, tid);
    float sn1 = bsum512f(ek1*ek1, w8b, tid);
    float n0 = sqrtf(sn0); if (n0 < 1e-12f) n0 = 1e-12f;
    float n1 = sqrtf(sn1); if (n1 < 1e-12f) n1 = 1e-12f;
    g_e[g][(size_t)r0*D     + tid] = ek0 / n0;
    g_e[g][(size_t)(r0+1)*D + tid] = ek1 / n1;
}

// P[v] = e1n[i1] . e2n[i2] ; 8 threads/output, float4-interleaved, 4 chains
__global__ void k_p() {
    int gidx = blockIdx.x*256 + threadIdx.x;      // 51200 threads
    int v = gidx >> 3, ch = gidx & 7;
    int i1 = v % N, i2 = v / N;
    const float4* a  = reinterpret_cast<const float4*>(g_e[0] + (size_t)i1*D);
    const float4* c2 = reinterpret_cast<const float4*>(g_e[1] + (size_t)i2*D);
    float a0=0,a1=0,a2=0,a3=0;
    #pragma unroll
    for (int t = 0; t < 16; ++t) {       // 16 float4 per lane
        float4 x = a[ch + 8*t], y = c2[ch + 8*t];
        a0 += x.x*y.x; a1 += x.y*y.y;
        a2 += x.z*y.z; a3 += x.w*y.w;
    }
    float s = (a0+a1)+(a2+a3);
    #pragma unroll
    for (int o = 1; o < 8; o <<= 1) s += __shfl_xor(s, o, 64);
    if (ch == 0) g_P[v] = s;
}

// Neumann solve on null(A) + clip + softmax + out; single block, f64 internal.
__global__ void __launch_bounds__(256,1) k_out(float* __restrict__ out) {
    __shared__ double sv[NV];
    __shared__ double sR[N], sC[N];
    __shared__ double ssc[4];
    __shared__ float  sox[N*(N+1)];   // padded transpose buffer
    const double inv80 = 1.0/80.0, inv6400 = 1.0/6400.0, CHI = 1.0/80.0;
    const double invCQ = 1.0/CQ;
    int tid = threadIdx.x;
    double ploc[25], vv[25], x[25];

    #pragma unroll
    for (int j = 0; j < 25; ++j) { int v = tid + 256*j; ploc[j] = (double)g_P[v]; sv[v] = ploc[j]; }
    __syncthreads();

    if (tid < N) {
        double cs = 0.0; const double* dd = sv + tid*N;
        for (int i1 = 0; i1 < N; ++i1) cs += dd[i1];
        sC[tid] = cs;
    } else if (tid < 2*N) {
        int i1 = tid - N; double rr = 0.0;
        for (int i2 = 0; i2 < N; ++i2) rr += sv[i2*N + i1];
        sR[i1] = rr;
    }
    __syncthreads();
    if (tid == 0) { double s = 0.0; for (int i = 0; i < N; ++i) s += sC[i]; ssc[0] = s; }
    __syncthreads();
    double Tp = ssc[0];
    const double SCALE = 6402.0/160.0;
    #pragma unroll
    for (int j = 0; j < 25; ++j) {
        int v = tid + 256*j; int i1 = v % N, i2 = v / N;
        double rv = SCALE*(ploc[j] - sR[i1]*inv80 - sC[i2]*inv80 + Tp*inv6400);
        vv[j] = rv;
        x[j]  = rv*invCQ;
    }
    __syncthreads();

    for (int k = 0; k < NEU_K; ++k) {
        #pragma unroll
        for (int j = 0; j < 25; ++j) { int v = tid + 256*j; sv[v] = ploc[j]*vv[j]; }
        __syncthreads();
        if (tid < N) {
            double cs = 0.0; const double* dd = sv + tid*N;
            for (int i1 = 0; i1 < N; ++i1) cs += dd[i1];
            sC[tid] = cs;
        } else if (tid < 2*N) {
            int i1 = tid - N; double rr = 0.0;
            for (int i2 = 0; i2 < N; ++i2) rr += sv[i2*N + i1];
            sR[i1] = rr;
        }
        __syncthreads();
        if (tid == 0) { double s = 0.0; for (int i = 0; i < N; ++i) s += sC[i]; ssc[1] = s; }
        __syncthreads();
        double Ty = ssc[1];
        #pragma unroll
        for (int j = 0; j < 25; ++j) {
            int v = tid + 256*j; int i1 = v % N, i2 = v / N;
            double mv = ploc[j]*vv[j] - sR[i1]*inv80 - sC[i2]*inv80 + Ty*inv6400;
            vv[j] = mv*invCQ;
            x[j] += vv[j]*invCQ;
        }
        __syncthreads();
    }

    #pragma unroll
    for (int j = 0; j < 25; ++j) {
        int v = tid + 256*j;
        double z = CHI + x[j];
        sv[v] = z < 0.0 ? 0.0 : (z > 1.0 ? 1.0 : z);
    }
    __syncthreads();
    if (tid < N) {
        double mx = -1e300;
        for (int i2 = 0; i2 < N; ++i2) mx = fmax(mx, sv[i2*N + tid]);
        sR[tid] = mx;
    }
    __syncthreads();
    #pragma unroll
    for (int j = 0; j < 25; ++j) {
        int v = tid + 256*j; int i1 = v % N;
        sv[v] = exp(1000.0*(sv[v] - sR[i1]));
    }
    __syncthreads();
    if (tid < N) {
        double s = 0.0;
        for (int i2 = 0; i2 < N; ++i2) s += sv[i2*N + tid];
        sC[tid] = 1.0 / s;
    }
    __syncthreads();
    #pragma unroll
    for (int j = 0; j < 25; ++j) {
        int v = tid + 256*j; int i1 = v % N, i2 = v / N;
        sox[i1*(N+1) + i2] = (float)(sv[v] * sC[i1]);
    }
    __syncthreads();
    for (int w = tid; w < NV; w += 256) {
        int i1 = w / N, i2 = w % N;
        out[w] = sox[i1*(N+1) + i2];
    }
}

extern "C" void kernel_launch(void* const* d_in, const int* in_sizes, int n_in,
                              void* d_out, int out_size, void* d_ws, size_t ws_size,
                              hipStream_t stream) {
    const float* d1 = (const float*)d_in[0];
    const float* d2 = (const float*)d_in[1];
    const float* W  = (const float*)d_in[2];
    const float* b  = (const float*)d_in[3];
    float* out = (float*)d_out;

    k_pre<<<dim3(456), dim3(256), 0, stream>>>(W, d1, d2);
    k_mue<<<dim3(80),  dim3(512), 0, stream>>>(d1, d2, b);
    k_p  <<<dim3(200), dim3(256), 0, stream>>>();
    k_out<<<dim3(1),   dim3(256), 0, stream>>>(out);
}

// Round 20
// 59.051 us; speedup vs baseline: 1.2787x; 1.2787x over previous
//
#include <hip/hip_runtime.h>
#include <math.h>

#define N 80
#define D 512
#define NV (N*N)        // 6400
#define CQ 6241.000001  // (n1-1)*(n2-1) + ridge
#define NEU_K 2         // truncation ~ ||r||/CQ^3 ~ 1.6e-10

// ---- static device scratch ----
__device__ double g_Mp0[N*N];
__device__ float  g_WT[D*D];        // W transposed
__device__ double g_e[2][N*D];      // normalized embeddings
__device__ double g_P[NV];          // p[v], v = i2*80 + i1

// k_pre: blocks 0..255 transpose W into WT (32x32 LDS tiles);
//        blocks 256..455 compute Mp0 = d1 @ d2^T (8 threads/output).
__global__ void k_pre(const float* __restrict__ W,
                      const float* __restrict__ d1, const float* __restrict__ d2) {
    int bid = blockIdx.x;
    int tid = threadIdx.x;
    if (bid < 256) {
        __shared__ float t[32][33];
        int c0 = (bid & 15)*32, k0 = (bid >> 4)*32;
        int tx = tid & 31, ty = tid >> 5;       // 32 x 8
        #pragma unroll
        for (int j = 0; j < 4; ++j) t[ty+8*j][tx] = W[(size_t)(k0+ty+8*j)*D + c0+tx];
        __syncthreads();
        #pragma unroll
        for (int j = 0; j < 4; ++j) g_WT[(size_t)(c0+ty+8*j)*D + k0+tx] = t[tx][ty+8*j];
    } else {
        int gidx = (bid-256)*256 + tid;         // 51200 threads
        int v = gidx >> 3, ch = gidx & 7;
        int i = v / N, j = v % N;
        const float4* A = reinterpret_cast<const float4*>(d1 + (size_t)i*D);
        const float4* B = reinterpret_cast<const float4*>(d2 + (size_t)j*D);
        double a0=0,a1=0,a2=0,a3=0;
        #pragma unroll
        for (int t = 0; t < 16; ++t) {
            float4 x = A[ch + 8*t], y = B[ch + 8*t];
            a0 += (double)x.x*(double)y.x; a1 += (double)x.y*(double)y.y;
            a2 += (double)x.z*(double)y.z; a3 += (double)x.w*(double)y.w;
        }
        double s = (a0+a1)+(a2+a3);
        #pragma unroll
        for (int o = 1; o < 8; o <<= 1) s += __shfl_xor(s, o, 64);
        if (ch == 0) g_Mp0[i*N+j] = s;
    }
}

// block-wide (512 thr) sum via wave shuffle + 8-slot LDS; 1 barrier + broadcast
__device__ __forceinline__ double bsum512(double v, double* w8, int tid) {
    #pragma unroll
    for (int o = 1; o < 64; o <<= 1) v += __shfl_xor(v, o, 64);
    if ((tid & 63) == 0) w8[tid >> 6] = v;
    __syncthreads();
    return ((w8[0]+w8[1])+(w8[2]+w8[3])) + ((w8[4]+w8[5])+(w8[6]+w8[7]));
}

// k_mue: fused m-row -> lam -> u -> e-row -> row-normalize.
// One block per (g,row), 512 threads, thread k owns output column k.
__global__ void __launch_bounds__(512,1) k_mue(const float* __restrict__ d1,
                                               const float* __restrict__ d2,
                                               const float* __restrict__ b) {
    __shared__ double mp[N];
    __shared__ double su[D];
    __shared__ double w8a[8], w8b[8];
    int bid = blockIdx.x;          // 0..159
    int g = bid / N, row = bid % N;
    int tid = threadIdx.x;         // = k
    const float* dsrc = g ? d1 : d2;    // summed rows for m
    const float* dme  = g ? d2 : d1;    // own data row

    if (tid < N) mp[tid] = g ? g_Mp0[tid*N + row] : g_Mp0[row*N + tid];
    __syncthreads();

    // m_k  (8 chains over 80 rows)
    double m0=0,m1=0,m2=0,m3=0,m4=0,m5=0,m6=0,m7=0;
    #pragma unroll 2
    for (int j = 0; j < N; j += 8) {
        m0 += mp[j]   * (double)dsrc[(size_t)j*D     + tid];
        m1 += mp[j+1] * (double)dsrc[(size_t)(j+1)*D + tid];
        m2 += mp[j+2] * (double)dsrc[(size_t)(j+2)*D + tid];
        m3 += mp[j+3] * (double)dsrc[(size_t)(j+3)*D + tid];
        m4 += mp[j+4] * (double)dsrc[(size_t)(j+4)*D + tid];
        m5 += mp[j+5] * (double)dsrc[(size_t)(j+5)*D + tid];
        m6 += mp[j+6] * (double)dsrc[(size_t)(j+6)*D + tid];
        m7 += mp[j+7] * (double)dsrc[(size_t)(j+7)*D + tid];
    }
    double mk = ((m0+m1)+(m2+m3)) + ((m4+m5)+(m6+m7));
    double ak = (double)dme[(size_t)row*D + tid];

    // lam = ||a|| / ||m||   (two shuffle-reductions, 1 barrier each)
    double sa = bsum512(ak*ak, w8a, tid);
    double sm = bsum512(mk*mk, w8b, tid);
    double lam = sqrt(sa) / sqrt(sm);
    __syncthreads();            // w8a/w8b reuse guard
    su[tid] = ak + lam*mk;
    __syncthreads();

    // e_k = relu(b_k + sum_c su[c]*WT[c][k])   (16 chains, coalesced WT)
    const float* wt = g_WT + tid;
    double a0=0,a1=0,a2=0,a3=0,a4=0,a5=0,a6=0,a7=0;
    double b0=0,b1=0,b2=0,b3=0,b4=0,b5=0,b6=0,b7=0;
    #pragma unroll 4
    for (int t = 0; t < 32; ++t) {
        int c = t*16;
        a0 += su[c+0]*(double)wt[(size_t)(c+0)*D];
        a1 += su[c+1]*(double)wt[(size_t)(c+1)*D];
        a2 += su[c+2]*(double)wt[(size_t)(c+2)*D];
        a3 += su[c+3]*(double)wt[(size_t)(c+3)*D];
        a4 += su[c+4]*(double)wt[(size_t)(c+4)*D];
        a5 += su[c+5]*(double)wt[(size_t)(c+5)*D];
        a6 += su[c+6]*(double)wt[(size_t)(c+6)*D];
        a7 += su[c+7]*(double)wt[(size_t)(c+7)*D];
        b0 += su[c+8]*(double)wt[(size_t)(c+8)*D];
        b1 += su[c+9]*(double)wt[(size_t)(c+9)*D];
        b2 += su[c+10]*(double)wt[(size_t)(c+10)*D];
        b3 += su[c+11]*(double)wt[(size_t)(c+11)*D];
        b4 += su[c+12]*(double)wt[(size_t)(c+12)*D];
        b5 += su[c+13]*(double)wt[(size_t)(c+13)*D];
        b6 += su[c+14]*(double)wt[(size_t)(c+14)*D];
        b7 += su[c+15]*(double)wt[(size_t)(c+15)*D];
    }
    double acc = (double)b[tid]
               + (((a0+a1)+(a2+a3)) + ((a4+a5)+(a6+a7)))
               + (((b0+b1)+(b2+b3)) + ((b4+b5)+(b6+b7)));
    double ek = acc > 0.0 ? acc : 0.0;

    // row normalize (shuffle reduction)
    double sn = bsum512(ek*ek, w8a, tid);
    double nrm = sqrt(sn); if (nrm < 1e-12) nrm = 1e-12;
    g_e[g][(size_t)row*D + tid] = ek / nrm;
}

// P[v] = e1n[i1] . e2n[i2] ; 8 threads/output, double2-interleaved, 4 chains
__global__ void k_p() {
    int gidx = blockIdx.x*256 + threadIdx.x;      // 51200 threads
    int v = gidx >> 3, ch = gidx & 7;
    int i1 = v % N, i2 = v / N;
    const double2* a = reinterpret_cast<const double2*>(g_e[0] + (size_t)i1*D);
    const double2* c2 = reinterpret_cast<const double2*>(g_e[1] + (size_t)i2*D);
    double a0=0,a1=0,a2=0,a3=0;
    #pragma unroll
    for (int t = 0; t < 32; t += 2) {
        double2 x = a[ch + 8*t],     y = c2[ch + 8*t];
        double2 x1 = a[ch + 8*t+8],  y1 = c2[ch + 8*t+8];
        a0 += x.x*y.x;  a1 += x.y*y.y;
        a2 += x1.x*y1.x; a3 += x1.y*y1.y;
    }
    double s = (a0+a1)+(a2+a3);
    #pragma unroll
    for (int o = 1; o < 8; o <<= 1) s += __shfl_xor(s, o, 64);
    if (ch == 0) g_P[v] = s;
}

// Neumann solve on null(A) + clip + softmax + out; single block.
// Final store coalesced via padded LDS transpose.
__global__ void __launch_bounds__(256,1) k_out(float* __restrict__ out) {
    __shared__ double sv[NV];
    __shared__ double sR[N], sC[N];
    __shared__ double ssc[4];
    __shared__ float  sox[N*(N+1)];   // padded transpose buffer (80x81 floats)
    const double inv80 = 1.0/80.0, inv6400 = 1.0/6400.0, CHI = 1.0/80.0;
    const double invCQ = 1.0/CQ;
    int tid = threadIdx.x;
    double ploc[25], vv[25], x[25];

    #pragma unroll
    for (int j = 0; j < 25; ++j) { int v = tid + 256*j; ploc[j] = g_P[v]; sv[v] = ploc[j]; }
    __syncthreads();

    if (tid < N) {
        double cs = 0.0; const double* dd = sv + tid*N;
        for (int i1 = 0; i1 < N; ++i1) cs += dd[i1];
        sC[tid] = cs;
    } else if (tid < 2*N) {
        int i1 = tid - N; double rr = 0.0;
        for (int i2 = 0; i2 < N; ++i2) rr += sv[i2*N + i1];
        sR[i1] = rr;
    }
    __syncthreads();
    if (tid == 0) { double s = 0.0; for (int i = 0; i < N; ++i) s += sC[i]; ssc[0] = s; }
    __syncthreads();
    double Tp = ssc[0];
    const double SCALE = 6402.0/160.0;
    #pragma unroll
    for (int j = 0; j < 25; ++j) {
        int v = tid + 256*j; int i1 = v % N, i2 = v / N;
        double rv = SCALE*(ploc[j] - sR[i1]*inv80 - sC[i2]*inv80 + Tp*inv6400);
        vv[j] = rv;
        x[j]  = rv*invCQ;
    }
    __syncthreads();

    for (int k = 0; k < NEU_K; ++k) {
        #pragma unroll
        for (int j = 0; j < 25; ++j) { int v = tid + 256*j; sv[v] = ploc[j]*vv[j]; }
        __syncthreads();
        if (tid < N) {
            double cs = 0.0; const double* dd = sv + tid*N;
            for (int i1 = 0; i1 < N; ++i1) cs += dd[i1];
            sC[tid] = cs;
        } else if (tid < 2*N) {
            int i1 = tid - N; double rr = 0.0;
            for (int i2 = 0; i2 < N; ++i2) rr += sv[i2*N + i1];
            sR[i1] = rr;
        }
        __syncthreads();
        if (tid == 0) { double s = 0.0; for (int i = 0; i < N; ++i) s += sC[i]; ssc[1] = s; }
        __syncthreads();
        double Ty = ssc[1];
        #pragma unroll
        for (int j = 0; j < 25; ++j) {
            int v = tid + 256*j; int i1 = v % N, i2 = v / N;
            double mv = ploc[j]*vv[j] - sR[i1]*inv80 - sC[i2]*inv80 + Ty*inv6400;
            vv[j] = mv*invCQ;
            x[j] += vv[j]*invCQ;
        }
        __syncthreads();
    }

    // z = clip(1/80 + x)
    #pragma unroll
    for (int j = 0; j < 25; ++j) {
        int v = tid + 256*j;
        double z = CHI + x[j];
        sv[v] = z < 0.0 ? 0.0 : (z > 1.0 ? 1.0 : z);
    }
    __syncthreads();
    // per-column (i1) max over i2
    if (tid < N) {
        double mx = -1e300;
        for (int i2 = 0; i2 < N; ++i2) mx = fmax(mx, sv[i2*N + tid]);
        sR[tid] = mx;
    }
    __syncthreads();
    #pragma unroll
    for (int j = 0; j < 25; ++j) {
        int v = tid + 256*j; int i1 = v % N;
        sv[v] = exp(1000.0*(sv[v] - sR[i1]));
    }
    __syncthreads();
    if (tid < N) {
        double s = 0.0;
        for (int i2 = 0; i2 < N; ++i2) s += sv[i2*N + tid];
        sC[tid] = 1.0 / s;
    }
    __syncthreads();
    // transpose into padded float buffer: sox[i1][i2] = sv[i2*N+i1]*sC[i1]
    #pragma unroll
    for (int j = 0; j < 25; ++j) {
        int v = tid + 256*j; int i1 = v % N, i2 = v / N;
        sox[i1*(N+1) + i2] = (float)(sv[v] * sC[i1]);
    }
    __syncthreads();
    // coalesced stores: consecutive tid -> consecutive out index
    for (int w = tid; w < NV; w += 256) {
        int i1 = w / N, i2 = w % N;
        out[w] = sox[i1*(N+1) + i2];
    }
}

extern "C" void kernel_launch(void* const* d_in, const int* in_sizes, int n_in,
                              void* d_out, int out_size, void* d_ws, size_t ws_size,
                              hipStream_t stream) {
    const float* d1 = (const float*)d_in[0];
    const float* d2 = (const float*)d_in[1];
    const float* W  = (const float*)d_in[2];
    const float* b  = (const float*)d_in[3];
    float* out = (float*)d_out;

    k_pre<<<dim3(456), dim3(256), 0, stream>>>(W, d1, d2);
    k_mue<<<dim3(160), dim3(512), 0, stream>>>(d1, d2, b);
    k_p  <<<dim3(200), dim3(256), 0, stream>>>();
    k_out<<<dim3(1),   dim3(256), 0, stream>>>(out);
}